// Round 10
// baseline (1855.801 us; speedup 1.0000x reference)
//
#include <hip/hip_runtime.h>
#include <hip/hip_bf16.h>

// MultiScaleAttention on MI355X (gfx950).
// R10: R9 with the spill fixed. R9's reg-staged A (fused permute+cvt) was
//     correct but __launch_bounds__(512,2) capped VGPRs at 128 while the
//     kernel needs ~128 VGPR + 128 AGPR + 64 VGPR for the A reg sets ->
//     scratch spill in the hot loop (WRITE +200MB, FETCH +1GB, MfmaUtil
//     33->10.6). LDS (128KiB) already limits to 1 block/CU, so the ,2 bound
//     bought nothing: now __launch_bounds__(512,1) -> ~320 regs/wave, 2
//     waves/SIMD x 320 = 640 << 2048 pool, same occupancy, no spill.
// QKV GEMM: A reg-staged directly from fp32 x (global_load_dwordx4 x2 /
//     quarter -> RNE bf16 pack -> ds_write_b128), window-major row permute
//     fused into per-thread A source addressing; B via global_load_lds.
//     Counted-vmcnt plan (all issues unconditional, clamped K-index):
//     ph0: vmcnt(4)->write buf1.A->issue A(t+2) | ph3: stage B(t+2),
//     vmcnt(12) | ph4: vmcnt(4)->write buf0.A->issue A(t+3) | ph7: stage
//     B(t+3), vmcnt(12). Region rewrites all >=1 barrier after last reader.
// GEMM core: 256x256, 8 waves, BK=64, 8-phase schedule, conflict-free
// XOR-swizzled LDS, bijective XCD swizzle, swapped-operand packed epilogue,
// window-major qkv output. attn: contiguous slabs, 40KB swizzled LDS,
// 4 blocks/CU. proj: R8 gload_lds plan.

typedef __bf16 bf16x8 __attribute__((ext_vector_type(8)));
typedef float f32x4 __attribute__((ext_vector_type(4)));

#define GLOBAL_AS __attribute__((address_space(1)))
#define LDS_AS __attribute__((address_space(3)))

__device__ __forceinline__ unsigned short f2bf(float f) {
    unsigned u = __builtin_bit_cast(unsigned, f);
    u += 0x7FFFu + ((u >> 16) & 1u);           // round-to-nearest-even
    return (unsigned short)(u >> 16);
}
__device__ __forceinline__ unsigned f2bf_u(unsigned u) {   // on raw f32 bits
    u += 0x7FFFu + ((u >> 16) & 1u);
    return u >> 16;
}
__device__ __forceinline__ float bf2f(unsigned short h) {
    return __builtin_bit_cast(float, (unsigned)h << 16);
}

__device__ __forceinline__ void load16_to_lds(const void* g, void* l) {
    __builtin_amdgcn_global_load_lds((const GLOBAL_AS unsigned int*)g,
                                     (LDS_AS unsigned int*)l, 16, 0, 0);
}

// ------------- fused W[K][N] fp32 -> Wt[N][K] bf16 (both weights) -------------
__global__ void transpose_cvt2(const float* __restrict__ W0,
                               unsigned short* __restrict__ T0,
                               const float* __restrict__ W1,
                               unsigned short* __restrict__ T1) {
    __shared__ float tile[32][33];
    int bxi = blockIdx.x;
    const float* W; unsigned short* Wt; int N;
    if (bxi < 72) { W = W0; Wt = T0; N = 2304; }
    else          { W = W1; Wt = T1; N = 768; bxi -= 72; }
    const int K = 768;
    int bx = bxi * 32;                         // N offset
    int by = blockIdx.y * 32;                  // K offset
    int tx = threadIdx.x & 31, ty = threadIdx.x >> 5;   // ty 0..7
    #pragma unroll
    for (int i = 0; i < 32; i += 8)
        tile[ty + i][tx] = W[(size_t)(by + ty + i) * N + bx + tx];
    __syncthreads();
    #pragma unroll
    for (int i = 0; i < 32; i += 8)
        Wt[(size_t)(bx + ty + i) * K + by + tx] = f2bf(tile[tx][ty + i]);
}

// ---------------- bf16 GEMM: C = A[M,K] @ Bt[N,K]^T + bias ----------------
// QKV=true : A is fp32 x (original [b][t*49+w][768] layout); rows virtually
//            window-major via per-thread source-row permute; A reg-staged
//            (fp32->bf16 in-kernel). Epilogue writes [b][w][3][12][64][64].
// QKV=false: A bf16, global_load_lds staging (R8 plan); fp32 [row][N] out.
#define VM_WAIT12 asm volatile("s_waitcnt vmcnt(12)" ::: "memory")
#define VM_WAIT4  asm volatile("s_waitcnt vmcnt(4)" ::: "memory")
#define VM_WAIT3  asm volatile("s_waitcnt vmcnt(3)" ::: "memory")
#define VM_WAIT2  asm volatile("s_waitcnt vmcnt(2)" ::: "memory")
#define VM_WAIT0  asm volatile("s_waitcnt vmcnt(0)" ::: "memory")

#define GPHASE(BUF, CSW, IH, LOADBG, STG, WAITS) do {                        \
    if (LOADBG) {                                                            \
        const unsigned short* bb = &ls[(BUF) * 32768 + 16384 + (CSW)];       \
        bg[0] = *(const bf16x8*)&bb[(wn +  0 + lane15) * 64];                \
        bg[1] = *(const bf16x8*)&bb[(wn + 16 + lane15) * 64];                \
        bg[2] = *(const bf16x8*)&bb[(wn + 32 + lane15) * 64];                \
        bg[3] = *(const bf16x8*)&bb[(wn + 48 + lane15) * 64];                \
    }                                                                        \
    {                                                                        \
        const unsigned short* ab = &ls[(BUF) * 32768 + (CSW)];               \
        af[0] = *(const bf16x8*)&ab[(wm + (IH)*64 +  0 + lane15) * 64];      \
        af[1] = *(const bf16x8*)&ab[(wm + (IH)*64 + 16 + lane15) * 64];      \
        af[2] = *(const bf16x8*)&ab[(wm + (IH)*64 + 32 + lane15) * 64];      \
        af[3] = *(const bf16x8*)&ab[(wm + (IH)*64 + 48 + lane15) * 64];      \
    }                                                                        \
    STG;                                                                     \
    WAITS;                                                                   \
    __builtin_amdgcn_s_barrier();                                            \
    asm volatile("s_waitcnt lgkmcnt(0)" ::: "memory");                       \
    __builtin_amdgcn_sched_barrier(0);                                       \
    __builtin_amdgcn_s_setprio(1);                                           \
    _Pragma("unroll")                                                        \
    for (int ii = 0; ii < 4; ++ii)                                           \
        _Pragma("unroll")                                                    \
        for (int j = 0; j < 4; ++j)                                          \
            acc[(IH)*4 + ii][j] = __builtin_amdgcn_mfma_f32_16x16x32_bf16(   \
                bg[j], af[ii], acc[(IH)*4 + ii][j], 0, 0, 0);                \
    __builtin_amdgcn_s_setprio(0);                                           \
    __builtin_amdgcn_s_barrier();                                            \
} while (0)

// issue 8 fp32 dwordx4 for one K-tile of A into register set AR[4][2]
#define ISSUE_A(AR, KT) do {                                                 \
    _Pragma("unroll")                                                        \
    for (int q = 0; q < 4; ++q) {                                            \
        const float* sp = gAqF[q] + (long)(KT) * 64;                         \
        AR[q][0] = *(const uint4*)sp;                                        \
        AR[q][1] = *(const uint4*)(sp + 4);                                  \
    }                                                                        \
} while (0)

// pack AR (8 fp32 bits per quarter) -> bf16x8 and ds_write into BUF's A region
#define WRITE_A(BUF, AR) do {                                                \
    _Pragma("unroll")                                                        \
    for (int q = 0; q < 4; ++q) {                                            \
        uint4 wv;                                                            \
        wv.x = f2bf_u(AR[q][0].x) | (f2bf_u(AR[q][0].y) << 16);              \
        wv.y = f2bf_u(AR[q][0].z) | (f2bf_u(AR[q][0].w) << 16);              \
        wv.z = f2bf_u(AR[q][1].x) | (f2bf_u(AR[q][1].y) << 16);              \
        wv.w = f2bf_u(AR[q][1].z) | (f2bf_u(AR[q][1].w) << 16);              \
        *(uint4*)&ls[(BUF) * 32768 + q * 4096 + ldsWaveBase + lane * 8] = wv;\
    }                                                                        \
} while (0)

template <bool QKV>
__global__ __launch_bounds__(512, 1)   // LDS caps at 1 block/CU; don't cap regs
void gemm_bt256(const void* __restrict__ Av,
                const unsigned short* __restrict__ Bt,
                const float* __restrict__ bias,
                void* __restrict__ Cv, int N, int K) {
    // ls[buf][op][256*64] ushorts; tile offset = buf*32768 + op*16384;
    // quarter q (64 rows) at +q*4096.
    __shared__ alignas(16) unsigned short ls[65536];       // 128 KiB

    const int tid  = threadIdx.x;
    const int lane = tid & 63;
    const int wave = tid >> 6;          // 0..7
    const int wm = (wave >> 2) * 128;   // 0 / 128
    const int wn = (wave & 3) * 64;     // 0 / 64 / 128 / 192
    const int lane15 = lane & 15;
    const int quad   = lane >> 4;
    const int csw0 = ((quad    ) ^ (lane & 7)) * 8;        // ks = 0
    const int csw1 = ((quad + 4) ^ (lane & 7)) * 8;        // ks = 32

    // bijective XCD swizzle (m204)
    const int nwg = (int)(gridDim.x * gridDim.y);
    const int hid = (int)(blockIdx.y * gridDim.x + blockIdx.x);
    const int q8  = nwg >> 3, r8 = nwg & 7;
    const int xcd = hid & 7;
    const int lid = (xcd < r8 ? xcd * (q8 + 1) : r8 * (q8 + 1) + (xcd - r8) * q8)
                    + (hid >> 3);
    const int tileX = lid % (int)gridDim.x;
    const int tileY = lid / (int)gridDim.x;
    const long bm = (long)tileY * 256;
    const long bn = (long)tileX * 256;

    // staging geometry: thread covers row (tid>>3) within each 64-row quarter,
    // physical chunk tid&7 -> logical chunk lc = (tid&7) ^ (row&7).
    const int r0 = tid >> 3;                               // 0..63
    const int lc = (tid & 7) ^ (r0 & 7);
    const int ldsWaveBase = wave * 512;    // ushorts (8 rows per wave)

    // A sources
    const float* gAqF[4];                                  // QKV: fp32 rows
    const unsigned short* gAq[4];                          // proj: bf16 rows
    #pragma unroll
    for (int q = 0; q < 4; ++q) {
        const int mq = (int)bm + q * 64 + r0;
        if constexpr (QKV) {
            const int b  = mq / 3136;
            const int r3 = mq - b * 3136;                  // = w*64 + t
            const long srow = (long)b * 3136 + (long)(r3 & 63) * 49 + (r3 >> 6);
            gAqF[q] = (const float*)Av + srow * 768 + lc * 8;
        } else {
            gAq[q] = (const unsigned short*)Av + (long)mq * K + lc * 8;
        }
    }
    const unsigned short* gB = Bt + (bn + r0) * (long)K + lc * 8;

    auto STAGE_A = [&](int buf, int q, int kt) {           // proj only
        load16_to_lds(gAq[q] + kt * 64,
                      &ls[buf * 32768 + q * 4096 + ldsWaveBase]);
    };
    auto STAGE_B = [&](int buf, int q, int kt) {
        load16_to_lds(gB + (long)q * 64 * K + kt * 64,
                      &ls[buf * 32768 + 16384 + q * 4096 + ldsWaveBase]);
    };

    f32x4 acc[8][4] = {};
    bf16x8 af[4], bg[4];

    const int NT = K >> 6;             // 12 K-tiles; NI = 6 iterations
    const int NI = NT >> 1;

    if constexpr (QKV) {
        uint4 arE[4][2], arO[4][2];
        // prologue -> steady invariant: buf0 ready, A(1)+B(1) in flight,
        // B(0) drained.
        ISSUE_A(arE, 0);
        WRITE_A(0, arE);               // compiler drains arE loads here
        STAGE_B(0, 0, 0); STAGE_B(0, 1, 0); STAGE_B(0, 2, 0); STAGE_B(0, 3, 0);
        ISSUE_A(arO, 1);
        STAGE_B(1, 0, 1); STAGE_B(1, 1, 1); STAGE_B(1, 2, 1); STAGE_B(1, 3, 1);
        VM_WAIT12;                     // drains B(0); leaves A(1)8+B(1)4
        __builtin_amdgcn_s_barrier();

        for (int i = 0; i < NI; ++i) {
            const int t2  = 2 * i;
            const int ka2 = (t2 + 2 < NT) ? t2 + 2 : NT - 1;   // clamped
            const int ka3 = (t2 + 3 < NT) ? t2 + 3 : NT - 1;
            // ph0: drain A(t2+1) regs (keep 4 B) -> write buf1.A -> issue A(t2+2)
            GPHASE(0, csw0, 0, 1,
                   { VM_WAIT4; WRITE_A(1, arO); ISSUE_A(arE, ka2); },
                   { (void)0; });
            GPHASE(0, csw0, 1, 0, { (void)0; }, { (void)0; });
            GPHASE(0, csw1, 0, 1, { (void)0; }, { (void)0; });
            // ph3: stage B(t2+2) into buf0.B; drain B(t2+1)
            GPHASE(0, csw1, 1, 0,
                   { STAGE_B(0, 0, ka2); STAGE_B(0, 1, ka2);
                     STAGE_B(0, 2, ka2); STAGE_B(0, 3, ka2); VM_WAIT12; },
                   { (void)0; });
            // ph4: drain A(t2+2) -> write buf0.A -> issue A(t2+3)
            GPHASE(1, csw0, 0, 1,
                   { VM_WAIT4; WRITE_A(0, arE); ISSUE_A(arO, ka3); },
                   { (void)0; });
            GPHASE(1, csw0, 1, 0, { (void)0; }, { (void)0; });
            GPHASE(1, csw1, 0, 1, { (void)0; }, { (void)0; });
            // ph7: stage B(t2+3) into buf1.B; drain B(t2+2)
            GPHASE(1, csw1, 1, 0,
                   { STAGE_B(1, 0, ka3); STAGE_B(1, 1, ka3);
                     STAGE_B(1, 2, ka3); STAGE_B(1, 3, ka3); VM_WAIT12; },
                   { (void)0; });
        }
    } else {
        // proj: R8 gload_lds plan (unchanged, verified)
        STAGE_A(0, 0, 0); STAGE_A(0, 1, 0); STAGE_A(0, 2, 0); STAGE_A(0, 3, 0);
        STAGE_B(0, 0, 0); STAGE_B(0, 1, 0); STAGE_B(0, 2, 0); STAGE_B(0, 3, 0);
        STAGE_A(1, 0, 1); STAGE_A(1, 2, 1);
        VM_WAIT2;
        __builtin_amdgcn_s_barrier();

        for (int i = 0; i < NI; ++i) {
            const int t2 = 2 * i;
            const bool last = (i == NI - 1);
            GPHASE(0, csw0, 0, 1,
                   { STAGE_A(1, 1, t2 + 1); STAGE_A(1, 3, t2 + 1); STAGE_B(1, 0, t2 + 1); },
                   { (void)0; });
            GPHASE(0, csw0, 1, 0,
                   { STAGE_B(1, 1, t2 + 1); STAGE_B(1, 2, t2 + 1); STAGE_B(1, 3, t2 + 1); },
                   { (void)0; });
            GPHASE(0, csw1, 0, 1, { (void)0; }, { (void)0; });
            GPHASE(0, csw1, 1, 0,
                   { if (!last) { STAGE_B(0, 0, t2 + 2); STAGE_B(0, 1, t2 + 2);
                                  STAGE_B(0, 2, t2 + 2); } },
                   { if (last) { VM_WAIT0; } else { VM_WAIT3; } });
            GPHASE(1, csw0, 0, 1,
                   { if (!last) { STAGE_B(0, 3, t2 + 2); STAGE_A(0, 0, t2 + 2);
                                  STAGE_A(0, 2, t2 + 2); } },
                   { (void)0; });
            GPHASE(1, csw0, 1, 0,
                   { if (!last) { STAGE_A(0, 1, t2 + 2); STAGE_A(0, 3, t2 + 2); } },
                   { (void)0; });
            GPHASE(1, csw1, 0, 1, { (void)0; }, { (void)0; });
            GPHASE(1, csw1, 1, 0,
                   { if (!last) { STAGE_A(1, 0, t2 + 3); STAGE_A(1, 2, t2 + 3); VM_WAIT2; } },
                   { (void)0; });
        }
    }

    // Epilogue: lane owns row = bm+wm+i*16+lane15, cols cbase..cbase+3.
    const int rbase = (int)(bm) + wm + lane15;
    if constexpr (QKV) {
        // QKV layout: [b][w][sec][h][t][d]; wave's 64-col slab = one (sec,h)
        const int colBase = (int)bn + wn;              // multiple of 64
        const int sec = colBase / 768;
        const int hh  = (colBase - sec * 768) >> 6;
        const long shOff = (long)sec * 49152 + hh * 4096 + quad * 4;
        unsigned short* qout = (unsigned short*)Cv;
        float4 bv[4];
        #pragma unroll
        for (int j = 0; j < 4; ++j)
            bv[j] = *(const float4*)&bias[colBase + quad * 4 + j * 16];
        #pragma unroll
        for (int i = 0; i < 8; ++i) {
            const int m  = rbase + i * 16;             // window-major token idx
            const int b  = m / 3136;
            const int r3 = m - b * 3136;               // = w*64 + t
            unsigned short* rp = qout + (long)(b * 49 + (r3 >> 6)) * 147456
                                      + shOff + (long)(r3 & 63) * 64;
            #pragma unroll
            for (int j = 0; j < 4; ++j) {
                ushort4 s;
                s.x = f2bf(acc[i][j][0] + bv[j].x);
                s.y = f2bf(acc[i][j][1] + bv[j].y);
                s.z = f2bf(acc[i][j][2] + bv[j].z);
                s.w = f2bf(acc[i][j][3] + bv[j].w);
                *(ushort4*)(rp + j * 16) = s;
            }
        }
    } else {
        const int cbase = (int)bn + wn + quad * 4;
        #pragma unroll
        for (int j = 0; j < 4; ++j) {
            const int col = cbase + j * 16;
            const float4 bv = *(const float4*)&bias[col];
            #pragma unroll
            for (int i = 0; i < 8; ++i) {
                const long row = (long)rbase + i * 16;
                const size_t idx = (size_t)row * N + col;
                float4 s;
                s.x = acc[i][j][0] + bv.x;
                s.y = acc[i][j][1] + bv.y;
                s.z = acc[i][j][2] + bv.z;
                s.w = acc[i][j][3] + bv.w;
                *(float4*)((float*)Cv + idx) = s;
            }
        }
    }
}

// ---------------- MFMA windowed attention ----------------
// qkv layout: [b][w][sec][h][t][d] (t=64 tokens, d=64) -> contiguous slabs.
// One wave = one (b,w,head); 4 waves/block. LDS 40960B (vT/ps stride 64 with
// XOR chunk swizzle: phys_chunk = logical_chunk ^ (row&7)) -> 4 blocks/CU.
__global__ __launch_bounds__(256, 4)
void attn_win_mfma(const unsigned short* __restrict__ qkv,
                   unsigned short* __restrict__ o) {
    const int hg = blockIdx.x;       // 0..2
    const int w  = blockIdx.y;       // 0..48
    const int b  = blockIdx.z;       // batch within chunk
    const int wave = threadIdx.x >> 6;
    const int lane = threadIdx.x & 63;
    const int h = hg * 4 + wave;
    const int l = lane & 15;
    const int quad = lane >> 4;

    __shared__ alignas(16) unsigned short vT[4][64 * 64];  // [d][t], swizzled
    __shared__ alignas(16) unsigned short ps[4][16 * 64];  // P[q][key], swizzled

    const long slab = (long)(b * 49 + w) * 147456;
    const long hOff = (long)h * 4096;

    // ---- q load + max-pool + 0.125 scale (exact in bf16) -> A-frags ----
    bf16x8 af[2];
    {
        const unsigned short* qr = qkv + slab + hOff + (long)l * 64 + quad * 8;
        float m0[8], m1[8];
        #pragma unroll
        for (int sg = 0; sg < 4; ++sg) {
            uint4 u0 = *(const uint4*)(qr + sg * 1024);
            uint4 u1 = *(const uint4*)(qr + sg * 1024 + 32);
            const unsigned short* p0 = (const unsigned short*)&u0;
            const unsigned short* p1 = (const unsigned short*)&u1;
            #pragma unroll
            for (int e = 0; e < 8; ++e) {
                float f0 = bf2f(p0[e]), f1 = bf2f(p1[e]);
                if (sg == 0) { m0[e] = f0; m1[e] = f1; }
                else { m0[e] = fmaxf(m0[e], f0); m1[e] = fmaxf(m1[e], f1); }
            }
        }
        unsigned short a0[8], a1[8];
        #pragma unroll
        for (int e = 0; e < 8; ++e) {
            a0[e] = f2bf(m0[e] * 0.125f);
            a1[e] = f2bf(m1[e] * 0.125f);
        }
        af[0] = __builtin_bit_cast(bf16x8, *(uint4*)a0);
        af[1] = __builtin_bit_cast(bf16x8, *(uint4*)a1);
    }

    // ---- v: stage transposed into LDS (XOR-swizzled, stride 64) ----
    {
        const unsigned short* vr = qkv + slab + 98304 + hOff + (long)lane * 64;
        unsigned short* vw = &vT[wave][0];
        const int ch = lane >> 3, le = lane & 7;
        #pragma unroll
        for (int i = 0; i < 8; ++i) {
            uint4 u = *(const uint4*)(vr + i * 8);
            const unsigned short* pe = (const unsigned short*)&u;
            #pragma unroll
            for (int e = 0; e < 8; ++e) {
                const int d = i * 8 + e;
                vw[d * 64 + ((ch ^ (d & 7)) << 3) + le] = pe[e];
            }
        }
    }

    // ---- k B-frags from global; S = qp @ k^T ----
    f32x4 Sc[4] = {};
    {
        bf16x8 bk0, bk1;
        __builtin_amdgcn_s_setprio(1);
        #pragma unroll
        for (int tt = 0; tt < 4; ++tt) {
            const unsigned short* kr =
                qkv + slab + 49152 + hOff + (long)(tt * 16 + l) * 64 + quad * 8;
            bk0 = __builtin_bit_cast(bf16x8, *(const uint4*)kr);
            bk1 = __builtin_bit_cast(bf16x8, *(const uint4*)(kr + 32));
            Sc[tt] = __builtin_amdgcn_mfma_f32_16x16x32_bf16(af[0], bk0, Sc[tt], 0, 0, 0);
            Sc[tt] = __builtin_amdgcn_mfma_f32_16x16x32_bf16(af[1], bk1, Sc[tt], 0, 0, 0);
        }
        __builtin_amdgcn_s_setprio(0);
    }

    // ---- softmax: row q = quad*4+r, keys spread over 4 tt x 16 lanes ----
    float pr[4][4];
    {
        #pragma unroll
        for (int r = 0; r < 4; ++r) {
            float mx = fmaxf(fmaxf(Sc[0][r], Sc[1][r]), fmaxf(Sc[2][r], Sc[3][r]));
            #pragma unroll
            for (int off = 1; off < 16; off <<= 1)
                mx = fmaxf(mx, __shfl_xor(mx, off));
            float sum = 0.f;
            #pragma unroll
            for (int tt = 0; tt < 4; ++tt) {
                pr[tt][r] = __expf(Sc[tt][r] - mx);
                sum += pr[tt][r];
            }
            #pragma unroll
            for (int off = 1; off < 16; off <<= 1)
                sum += __shfl_xor(sum, off);
            const float inv = 1.0f / sum;
            #pragma unroll
            for (int tt = 0; tt < 4; ++tt) pr[tt][r] *= inv;
        }
    }

    // ---- P -> LDS (bf16, XOR-swizzled, stride 64) ----
    {
        unsigned short* pw = &ps[wave][0];
        #pragma unroll
        for (int r = 0; r < 4; ++r) {
            const int row = quad * 4 + r;
            #pragma unroll
            for (int tt = 0; tt < 4; ++tt) {
                const int c = (tt << 1) + (l >> 3);
                pw[row * 64 + ((c ^ (row & 7)) << 3) + (l & 7)] = f2bf(pr[tt][r]);
            }
        }
    }

    // ---- O = P @ v ----
    f32x4 Oc[4] = {};
    {
        __builtin_amdgcn_s_setprio(1);
        #pragma unroll
        for (int s = 0; s < 2; ++s) {
            const int csw = (((s << 2) + quad) ^ (l & 7)) << 3;
            bf16x8 ap = *(const bf16x8*)&ps[wave][l * 64 + csw];
            #pragma unroll
            for (int tt = 0; tt < 4; ++tt) {
                bf16x8 bv = *(const bf16x8*)&vT[wave][(tt * 16 + l) * 64 + csw];
                Oc[tt] = __builtin_amdgcn_mfma_f32_16x16x32_bf16(ap, bv, Oc[tt], 0, 0, 0);
            }
        }
        __builtin_amdgcn_s_setprio(0);
    }

    // ---- store: o row = b*784 + q*49 + w, col = h*64 + tt*16 + l ----
    {
        const long obase = ((long)b * 784 + (long)(quad * 4) * 49 + w) * 768 + h * 64 + l;
        #pragma unroll
        for (int tt = 0; tt < 4; ++tt)
            #pragma unroll
            for (int r = 0; r < 4; ++r)
                o[obase + (long)r * 49 * 768 + tt * 16] = f2bf(Oc[tt][r]);
    }
}

// ---------------- launcher ----------------
extern "C" void kernel_launch(void* const* d_in, const int* in_sizes, int n_in,
                              void* d_out, int out_size, void* d_ws, size_t ws_size,
                              hipStream_t stream) {
    const float* x     = (const float*)d_in[0];  // [32,3136,768]
    const float* Wqkv  = (const float*)d_in[1];  // [768,2304]
    const float* bqkv  = (const float*)d_in[2];  // [2304]
    const float* Wproj = (const float*)d_in[3];  // [768,768]
    const float* bproj = (const float*)d_in[4];  // [768]
    float* out = (float*)d_out;                  // [32,784,768] fp32

    const long needed1 = (32L * 3136 * 2304 +
                          25088L * 768 + 2304L * 768 + 768L * 768) * 2;
    const int C  = (ws_size >= (size_t)needed1) ? 1 : 4;   // unchunked if ws allows
    const int CB = 32 / C;
    const long QC = (long)CB * 3136 * 2304;

    char* p = (char*)d_ws;
    unsigned short* qkvb  = (unsigned short*)p; p += QC * 2;
    unsigned short* ob    = (unsigned short*)p; p += 25088L * 768 * 2;
    unsigned short* WqkvT = (unsigned short*)p; p += 2304L * 768 * 2;
    unsigned short* WprojT= (unsigned short*)p; p += 768L * 768 * 2;

    transpose_cvt2<<<dim3(96, 24), 256, 0, stream>>>(Wqkv, WqkvT, Wproj, WprojT);

    const int M = CB * 3136;
    for (int c = 0; c < C; ++c) {
        gemm_bt256<true><<<dim3(9, M / 256), 512, 0, stream>>>(
            x + (size_t)c * M * 768, WqkvT, bqkv, qkvb, 2304, 768);
        attn_win_mfma<<<dim3(3, 49, CB), 256, 0, stream>>>(
            qkvb, ob + (size_t)c * CB * 784 * 768);
    }
    gemm_bt256<false><<<dim3(3, 98), 512, 0, stream>>>(
        ob, WprojT, bproj, out, 768, 768);
}

// Round 11
// 1057.242 us; speedup vs baseline: 1.7553x; 1.7553x over previous
//
#include <hip/hip_runtime.h>
#include <hip/hip_bf16.h>

// MultiScaleAttention on MI355X (gfx950).
// R11: REVERT to R8 (best verified: 1059us). R9/R10's reg-staged A was
//     structurally infeasible: 512-thr block = 2 waves/SIMD min -> 256
//     unified regs/wave cap; acc eats 128 AGPRs; R8's path already uses the
//     remaining 128 VGPRs fully -> the +64-VGPR A-reg sets must spill
//     (measured both rounds: FETCH +1GB scratch, MfmaUtil 33->10.5).
// Pipeline: transpose weights -> per chunk {cvt fp32->bf16 (streaming),
//     QKV GEMM (bf16, gload_lds, window-major output), attn} -> proj.
// GEMM core: 256x256 tile, 8 waves, BK=64, 8-phase counted-vmcnt schedule
//     (stage plan: every load >=2 phases in flight), conflict-free
//     XOR-swizzled LDS (0 conflicts), bijective XCD swizzle, swapped-operand
//     packed epilogue; QKV epilogue writes [b][w][3][12][64][64] bf16 with
//     the window-major row permute fused into A source addressing.
// attn: window-contiguous slabs, 40KB XOR-swizzled LDS, 4 blocks/CU,
//     setprio around MFMA clusters.

typedef __bf16 bf16x8 __attribute__((ext_vector_type(8)));
typedef float f32x4 __attribute__((ext_vector_type(4)));

#define GLOBAL_AS __attribute__((address_space(1)))
#define LDS_AS __attribute__((address_space(3)))

__device__ __forceinline__ unsigned short f2bf(float f) {
    unsigned u = __builtin_bit_cast(unsigned, f);
    u += 0x7FFFu + ((u >> 16) & 1u);           // round-to-nearest-even
    return (unsigned short)(u >> 16);
}
__device__ __forceinline__ float bf2f(unsigned short h) {
    return __builtin_bit_cast(float, (unsigned)h << 16);
}

__device__ __forceinline__ void load16_to_lds(const void* g, void* l) {
    __builtin_amdgcn_global_load_lds((const GLOBAL_AS unsigned int*)g,
                                     (LDS_AS unsigned int*)l, 16, 0, 0);
}

// ---------------- pure streaming fp32 -> bf16 (16B out / thread) ----------------
__global__ __launch_bounds__(256)
void cvt_f32_bf16(const float* __restrict__ in,
                  unsigned short* __restrict__ out, long n8) {
    const long i = (long)blockIdx.x * blockDim.x + threadIdx.x;  // 8-elem unit
    if (i >= n8) return;
    float4 f0 = ((const float4*)in)[i * 2];
    float4 f1 = ((const float4*)in)[i * 2 + 1];
    uint4 o;
    o.x = (unsigned)f2bf(f0.x) | ((unsigned)f2bf(f0.y) << 16);
    o.y = (unsigned)f2bf(f0.z) | ((unsigned)f2bf(f0.w) << 16);
    o.z = (unsigned)f2bf(f1.x) | ((unsigned)f2bf(f1.y) << 16);
    o.w = (unsigned)f2bf(f1.z) | ((unsigned)f2bf(f1.w) << 16);
    ((uint4*)out)[i] = o;
}

// ------------- fused W[K][N] fp32 -> Wt[N][K] bf16 (both weights) -------------
__global__ void transpose_cvt2(const float* __restrict__ W0,
                               unsigned short* __restrict__ T0,
                               const float* __restrict__ W1,
                               unsigned short* __restrict__ T1) {
    __shared__ float tile[32][33];
    int bxi = blockIdx.x;
    const float* W; unsigned short* Wt; int N;
    if (bxi < 72) { W = W0; Wt = T0; N = 2304; }
    else          { W = W1; Wt = T1; N = 768; bxi -= 72; }
    const int K = 768;
    int bx = bxi * 32;                         // N offset
    int by = blockIdx.y * 32;                  // K offset
    int tx = threadIdx.x & 31, ty = threadIdx.x >> 5;   // ty 0..7
    #pragma unroll
    for (int i = 0; i < 32; i += 8)
        tile[ty + i][tx] = W[(size_t)(by + ty + i) * N + bx + tx];
    __syncthreads();
    #pragma unroll
    for (int i = 0; i < 32; i += 8)
        Wt[(size_t)(bx + ty + i) * K + by + tx] = f2bf(tile[tx][ty + i]);
}

// ---------------- bf16 GEMM: C = A[M,K] @ Bt[N,K]^T + bias ----------------
// QKV=true : A rows are VIRTUALLY window-major — source row for output row m'
//            is b*3136 + t*49 + w (per-thread, precomputed); epilogue writes
//            [b][w][3][12][64][64] bf16.
// QKV=false: plain A rows; canonical fp32 [row][N] out.
#define VM_WAIT3 asm volatile("s_waitcnt vmcnt(3)" ::: "memory")
#define VM_WAIT2 asm volatile("s_waitcnt vmcnt(2)" ::: "memory")
#define VM_WAIT0 asm volatile("s_waitcnt vmcnt(0)" ::: "memory")

#define GPHASE(BUF, CSW, IH, LOADBG, STG, WAITS) do {                        \
    if (LOADBG) {                                                            \
        const unsigned short* bb = &ls[(BUF) * 32768 + 16384 + (CSW)];       \
        bg[0] = *(const bf16x8*)&bb[(wn +  0 + lane15) * 64];                \
        bg[1] = *(const bf16x8*)&bb[(wn + 16 + lane15) * 64];                \
        bg[2] = *(const bf16x8*)&bb[(wn + 32 + lane15) * 64];                \
        bg[3] = *(const bf16x8*)&bb[(wn + 48 + lane15) * 64];                \
    }                                                                        \
    {                                                                        \
        const unsigned short* ab = &ls[(BUF) * 32768 + (CSW)];               \
        af[0] = *(const bf16x8*)&ab[(wm + (IH)*64 +  0 + lane15) * 64];      \
        af[1] = *(const bf16x8*)&ab[(wm + (IH)*64 + 16 + lane15) * 64];      \
        af[2] = *(const bf16x8*)&ab[(wm + (IH)*64 + 32 + lane15) * 64];      \
        af[3] = *(const bf16x8*)&ab[(wm + (IH)*64 + 48 + lane15) * 64];      \
    }                                                                        \
    STG;                                                                     \
    WAITS;                                                                   \
    __builtin_amdgcn_s_barrier();                                            \
    asm volatile("s_waitcnt lgkmcnt(0)" ::: "memory");                       \
    __builtin_amdgcn_sched_barrier(0);                                       \
    __builtin_amdgcn_s_setprio(1);                                           \
    _Pragma("unroll")                                                        \
    for (int ii = 0; ii < 4; ++ii)                                           \
        _Pragma("unroll")                                                    \
        for (int j = 0; j < 4; ++j)                                          \
            acc[(IH)*4 + ii][j] = __builtin_amdgcn_mfma_f32_16x16x32_bf16(   \
                bg[j], af[ii], acc[(IH)*4 + ii][j], 0, 0, 0);                \
    __builtin_amdgcn_s_setprio(0);                                           \
    __builtin_amdgcn_s_barrier();                                            \
} while (0)

template <bool QKV>
__global__ __launch_bounds__(512, 2)
void gemm_bt256(const unsigned short* __restrict__ A,
                const unsigned short* __restrict__ Bt,
                const float* __restrict__ bias,
                void* __restrict__ Cv, int N, int K) {
    // ls[buf][op][256*64] ushorts; tile offset = buf*32768 + op*16384;
    // quarter q (64 rows) at +q*4096.
    __shared__ alignas(16) unsigned short ls[65536];       // 128 KiB

    const int tid  = threadIdx.x;
    const int lane = tid & 63;
    const int wave = tid >> 6;          // 0..7
    const int wm = (wave >> 2) * 128;   // 0 / 128
    const int wn = (wave & 3) * 64;     // 0 / 64 / 128 / 192
    const int lane15 = lane & 15;
    const int quad   = lane >> 4;
    // logical chunk (ks/8 + quad) -> physical = logical ^ (row&7), row&7 = lane&7
    const int csw0 = ((quad    ) ^ (lane & 7)) * 8;        // ks = 0
    const int csw1 = ((quad + 4) ^ (lane & 7)) * 8;        // ks = 32

    // bijective XCD swizzle (m204)
    const int nwg = (int)(gridDim.x * gridDim.y);
    const int hid = (int)(blockIdx.y * gridDim.x + blockIdx.x);
    const int q8  = nwg >> 3, r8 = nwg & 7;
    const int xcd = hid & 7;
    const int lid = (xcd < r8 ? xcd * (q8 + 1) : r8 * (q8 + 1) + (xcd - r8) * q8)
                    + (hid >> 3);
    const int tileX = lid % (int)gridDim.x;
    const int tileY = lid / (int)gridDim.x;
    const long bm = (long)tileY * 256;
    const long bn = (long)tileX * 256;

    // staging: thread covers row (tid>>3) within each 64-row quarter, physical
    // chunk tid&7 -> global (logical) chunk lc = (tid&7) ^ (row&7).
    const int r0 = tid >> 3;                               // 0..63
    const int lc = (tid & 7) ^ (r0 & 7);
    // Per-quarter A source rows. QKV: output row m' = bm + q*64 + r0 is a
    // window-major token (b = m'/3136, r3 = m'%3136, w = r3>>6, t = r3&63);
    // source row in the UNPERMUTED xb is b*3136 + t*49 + w.
    const unsigned short* gAq[4];
    #pragma unroll
    for (int q = 0; q < 4; ++q) {
        const int mq = (int)bm + q * 64 + r0;
        long srow;
        if constexpr (QKV) {
            const int b  = mq / 3136;
            const int r3 = mq - b * 3136;
            srow = (long)b * 3136 + (long)(r3 & 63) * 49 + (r3 >> 6);
        } else {
            srow = mq;
        }
        gAq[q] = A + srow * (long)K + lc * 8;
    }
    const unsigned short* gB = Bt + (bn + r0) * (long)K + lc * 8;
    const int ldsWaveBase = wave * 512;    // ushorts (8 rows per wave)

    auto STAGE_A = [&](int buf, int q, int kt) {
        load16_to_lds(gAq[q] + kt * 64,
                      &ls[buf * 32768 + q * 4096 + ldsWaveBase]);
    };
    auto STAGE_B = [&](int buf, int q, int kt) {
        load16_to_lds(gB + (long)q * 64 * K + kt * 64,
                      &ls[buf * 32768 + 16384 + q * 4096 + ldsWaveBase]);
    };

    f32x4 acc[8][4] = {};
    bf16x8 af[4], bg[4];

    const int NT = K >> 6;             // K-tiles (12); NI = NT/2 iterations
    const int NI = NT >> 1;

    // prologue: K-tile 0 (8 quarters) + K-tile 1 A-q0/q2 -> 10 loads
    STAGE_A(0, 0, 0); STAGE_A(0, 1, 0); STAGE_A(0, 2, 0); STAGE_A(0, 3, 0);
    STAGE_B(0, 0, 0); STAGE_B(0, 1, 0); STAGE_B(0, 2, 0); STAGE_B(0, 3, 0);
    STAGE_A(1, 0, 1); STAGE_A(1, 2, 1);
    VM_WAIT2;                           // K-tile 0 landed (A1q0,q2 in flight)
    __builtin_amdgcn_s_barrier();

    for (int i = 0; i < NI; ++i) {
        const int t2 = 2 * i;
        const bool last = (i == NI - 1);
        // ph0..3: consume buf0 (K-tile t2); ph4..7: buf1 (K-tile t2+1)
        // Stage plan (every load >= 2 phases in flight before its drain):
        //   ph0: A1q1,A1q3,B1q0(t+1) | ph1: B1q1..q3 | ph2: -
        //   ph3: B0q0..q2(t+2) + vmcnt(3) | ph4: B0q3,A0q0,A0q2
        //   ph5: A0q1,A0q3 | ph6: - | ph7: A1q0,A1q2(t+3) + vmcnt(2)
        GPHASE(0, csw0, 0, 1,
               { STAGE_A(1, 1, t2 + 1); STAGE_A(1, 3, t2 + 1); STAGE_B(1, 0, t2 + 1); },
               { (void)0; });
        GPHASE(0, csw0, 1, 0,
               { STAGE_B(1, 1, t2 + 1); STAGE_B(1, 2, t2 + 1); STAGE_B(1, 3, t2 + 1); },
               { (void)0; });
        GPHASE(0, csw1, 0, 1, { (void)0; }, { (void)0; });
        GPHASE(0, csw1, 1, 0,
               { if (!last) { STAGE_B(0, 0, t2 + 2); STAGE_B(0, 1, t2 + 2);
                              STAGE_B(0, 2, t2 + 2); } },
               { if (last) { VM_WAIT0; } else { VM_WAIT3; } });
        GPHASE(1, csw0, 0, 1,
               { if (!last) { STAGE_B(0, 3, t2 + 2); STAGE_A(0, 0, t2 + 2);
                              STAGE_A(0, 2, t2 + 2); } },
               { (void)0; });
        GPHASE(1, csw0, 1, 0,
               { if (!last) { STAGE_A(0, 1, t2 + 2); STAGE_A(0, 3, t2 + 2); } },
               { (void)0; });
        GPHASE(1, csw1, 0, 1, { (void)0; }, { (void)0; });
        GPHASE(1, csw1, 1, 0,
               { if (!last) { STAGE_A(1, 0, t2 + 3); STAGE_A(1, 2, t2 + 3); VM_WAIT2; } },
               { (void)0; });
    }

    // Epilogue: lane owns row = bm+wm+i*16+lane15, cols cbase..cbase+3.
    const int rbase = (int)(bm) + wm + lane15;
    if constexpr (QKV) {
        // QKV layout: [b][w][sec][h][t][d]; wave's 64-col slab = one (sec,h)
        const int colBase = (int)bn + wn;              // multiple of 64
        const int sec = colBase / 768;
        const int hh  = (colBase - sec * 768) >> 6;
        const long shOff = (long)sec * 49152 + hh * 4096 + quad * 4;
        unsigned short* qout = (unsigned short*)Cv;
        float4 bv[4];
        #pragma unroll
        for (int j = 0; j < 4; ++j)
            bv[j] = *(const float4*)&bias[colBase + quad * 4 + j * 16];
        #pragma unroll
        for (int i = 0; i < 8; ++i) {
            const int m  = rbase + i * 16;             // window-major token idx
            const int b  = m / 3136;
            const int r3 = m - b * 3136;               // = w*64 + t
            unsigned short* rp = qout + (long)(b * 49 + (r3 >> 6)) * 147456
                                      + shOff + (long)(r3 & 63) * 64;
            #pragma unroll
            for (int j = 0; j < 4; ++j) {
                ushort4 s;
                s.x = f2bf(acc[i][j][0] + bv[j].x);
                s.y = f2bf(acc[i][j][1] + bv[j].y);
                s.z = f2bf(acc[i][j][2] + bv[j].z);
                s.w = f2bf(acc[i][j][3] + bv[j].w);
                *(ushort4*)(rp + j * 16) = s;
            }
        }
    } else {
        const int cbase = (int)bn + wn + quad * 4;
        #pragma unroll
        for (int j = 0; j < 4; ++j) {
            const int col = cbase + j * 16;
            const float4 bv = *(const float4*)&bias[col];
            #pragma unroll
            for (int i = 0; i < 8; ++i) {
                const long row = (long)rbase + i * 16;
                const size_t idx = (size_t)row * N + col;
                float4 s;
                s.x = acc[i][j][0] + bv.x;
                s.y = acc[i][j][1] + bv.y;
                s.z = acc[i][j][2] + bv.z;
                s.w = acc[i][j][3] + bv.w;
                *(float4*)((float*)Cv + idx) = s;
            }
        }
    }
}

// ---------------- MFMA windowed attention ----------------
// qkv layout: [b][w][sec][h][t][d] (t=64 tokens, d=64) -> contiguous slabs.
// One wave = one (b,w,head); 4 waves/block. LDS 40960B (vT/ps stride 64 with
// XOR chunk swizzle: phys_chunk = logical_chunk ^ (row&7)) -> 4 blocks/CU.
__global__ __launch_bounds__(256, 4)
void attn_win_mfma(const unsigned short* __restrict__ qkv,
                   unsigned short* __restrict__ o) {
    const int hg = blockIdx.x;       // 0..2
    const int w  = blockIdx.y;       // 0..48
    const int b  = blockIdx.z;       // batch within chunk
    const int wave = threadIdx.x >> 6;
    const int lane = threadIdx.x & 63;
    const int h = hg * 4 + wave;
    const int l = lane & 15;
    const int quad = lane >> 4;

    __shared__ alignas(16) unsigned short vT[4][64 * 64];  // [d][t], swizzled
    __shared__ alignas(16) unsigned short ps[4][16 * 64];  // P[q][key], swizzled

    const long slab = (long)(b * 49 + w) * 147456;
    const long hOff = (long)h * 4096;

    // ---- q load + max-pool + 0.125 scale (exact in bf16) -> A-frags ----
    bf16x8 af[2];
    {
        const unsigned short* qr = qkv + slab + hOff + (long)l * 64 + quad * 8;
        float m0[8], m1[8];
        #pragma unroll
        for (int sg = 0; sg < 4; ++sg) {
            uint4 u0 = *(const uint4*)(qr + sg * 1024);
            uint4 u1 = *(const uint4*)(qr + sg * 1024 + 32);
            const unsigned short* p0 = (const unsigned short*)&u0;
            const unsigned short* p1 = (const unsigned short*)&u1;
            #pragma unroll
            for (int e = 0; e < 8; ++e) {
                float f0 = bf2f(p0[e]), f1 = bf2f(p1[e]);
                if (sg == 0) { m0[e] = f0; m1[e] = f1; }
                else { m0[e] = fmaxf(m0[e], f0); m1[e] = fmaxf(m1[e], f1); }
            }
        }
        unsigned short a0[8], a1[8];
        #pragma unroll
        for (int e = 0; e < 8; ++e) {
            a0[e] = f2bf(m0[e] * 0.125f);
            a1[e] = f2bf(m1[e] * 0.125f);
        }
        af[0] = __builtin_bit_cast(bf16x8, *(uint4*)a0);
        af[1] = __builtin_bit_cast(bf16x8, *(uint4*)a1);
    }

    // ---- v: stage transposed into LDS (XOR-swizzled, stride 64) ----
    {
        const unsigned short* vr = qkv + slab + 98304 + hOff + (long)lane * 64;
        unsigned short* vw = &vT[wave][0];
        const int ch = lane >> 3, le = lane & 7;
        #pragma unroll
        for (int i = 0; i < 8; ++i) {
            uint4 u = *(const uint4*)(vr + i * 8);
            const unsigned short* pe = (const unsigned short*)&u;
            #pragma unroll
            for (int e = 0; e < 8; ++e) {
                const int d = i * 8 + e;
                vw[d * 64 + ((ch ^ (d & 7)) << 3) + le] = pe[e];
            }
        }
    }

    // ---- k B-frags from global; S = qp @ k^T ----
    f32x4 Sc[4] = {};
    {
        bf16x8 bk0, bk1;
        __builtin_amdgcn_s_setprio(1);
        #pragma unroll
        for (int tt = 0; tt < 4; ++tt) {
            const unsigned short* kr =
                qkv + slab + 49152 + hOff + (long)(tt * 16 + l) * 64 + quad * 8;
            bk0 = __builtin_bit_cast(bf16x8, *(const uint4*)kr);
            bk1 = __builtin_bit_cast(bf16x8, *(const uint4*)(kr + 32));
            Sc[tt] = __builtin_amdgcn_mfma_f32_16x16x32_bf16(af[0], bk0, Sc[tt], 0, 0, 0);
            Sc[tt] = __builtin_amdgcn_mfma_f32_16x16x32_bf16(af[1], bk1, Sc[tt], 0, 0, 0);
        }
        __builtin_amdgcn_s_setprio(0);
    }

    // ---- softmax: row q = quad*4+r, keys spread over 4 tt x 16 lanes ----
    float pr[4][4];
    {
        #pragma unroll
        for (int r = 0; r < 4; ++r) {
            float mx = fmaxf(fmaxf(Sc[0][r], Sc[1][r]), fmaxf(Sc[2][r], Sc[3][r]));
            #pragma unroll
            for (int off = 1; off < 16; off <<= 1)
                mx = fmaxf(mx, __shfl_xor(mx, off));
            float sum = 0.f;
            #pragma unroll
            for (int tt = 0; tt < 4; ++tt) {
                pr[tt][r] = __expf(Sc[tt][r] - mx);
                sum += pr[tt][r];
            }
            #pragma unroll
            for (int off = 1; off < 16; off <<= 1)
                sum += __shfl_xor(sum, off);
            const float inv = 1.0f / sum;
            #pragma unroll
            for (int tt = 0; tt < 4; ++tt) pr[tt][r] *= inv;
        }
    }

    // ---- P -> LDS (bf16, XOR-swizzled, stride 64) ----
    {
        unsigned short* pw = &ps[wave][0];
        #pragma unroll
        for (int r = 0; r < 4; ++r) {
            const int row = quad * 4 + r;
            #pragma unroll
            for (int tt = 0; tt < 4; ++tt) {
                const int c = (tt << 1) + (l >> 3);
                pw[row * 64 + ((c ^ (row & 7)) << 3) + (l & 7)] = f2bf(pr[tt][r]);
            }
        }
    }

    // ---- O = P @ v ----
    f32x4 Oc[4] = {};
    {
        __builtin_amdgcn_s_setprio(1);
        #pragma unroll
        for (int s = 0; s < 2; ++s) {
            const int csw = (((s << 2) + quad) ^ (l & 7)) << 3;
            bf16x8 ap = *(const bf16x8*)&ps[wave][l * 64 + csw];
            #pragma unroll
            for (int tt = 0; tt < 4; ++tt) {
                bf16x8 bv = *(const bf16x8*)&vT[wave][(tt * 16 + l) * 64 + csw];
                Oc[tt] = __builtin_amdgcn_mfma_f32_16x16x32_bf16(ap, bv, Oc[tt], 0, 0, 0);
            }
        }
        __builtin_amdgcn_s_setprio(0);
    }

    // ---- store: o row = b*784 + q*49 + w, col = h*64 + tt*16 + l ----
    {
        const long obase = ((long)b * 784 + (long)(quad * 4) * 49 + w) * 768 + h * 64 + l;
        #pragma unroll
        for (int tt = 0; tt < 4; ++tt)
            #pragma unroll
            for (int r = 0; r < 4; ++r)
                o[obase + (long)r * 49 * 768 + tt * 16] = f2bf(Oc[tt][r]);
    }
}

// ---------------- launcher ----------------
extern "C" void kernel_launch(void* const* d_in, const int* in_sizes, int n_in,
                              void* d_out, int out_size, void* d_ws, size_t ws_size,
                              hipStream_t stream) {
    const float* x     = (const float*)d_in[0];  // [32,3136,768]
    const float* Wqkv  = (const float*)d_in[1];  // [768,2304]
    const float* bqkv  = (const float*)d_in[2];  // [2304]
    const float* Wproj = (const float*)d_in[3];  // [768,768]
    const float* bproj = (const float*)d_in[4];  // [768]
    float* out = (float*)d_out;                  // [32,784,768] fp32

    const long needed1 = (32L * 3136 * 768 + 32L * 3136 * 2304 +
                          25088L * 768 + 2304L * 768 + 768L * 768) * 2;
    const int C  = (ws_size >= (size_t)needed1) ? 1 : 4;   // unchunked if ws allows
    const int CB = 32 / C;
    const long XC = (long)CB * 3136 * 768;
    const long QC = (long)CB * 3136 * 2304;

    char* p = (char*)d_ws;
    unsigned short* xb    = (unsigned short*)p; p += XC * 2;
    unsigned short* qkvb  = (unsigned short*)p; p += QC * 2;
    unsigned short* ob    = (unsigned short*)p; p += 25088L * 768 * 2;
    unsigned short* WqkvT = (unsigned short*)p; p += 2304L * 768 * 2;
    unsigned short* WprojT= (unsigned short*)p; p += 768L * 768 * 2;

    transpose_cvt2<<<dim3(96, 24), 256, 0, stream>>>(Wqkv, WqkvT, Wproj, WprojT);

    const int M = CB * 3136;
    for (int c = 0; c < C; ++c) {
        cvt_f32_bf16<<<(int)((M * 96L + 255) / 256), 256, 0, stream>>>(
            x + (size_t)c * XC, xb, M * 96L);
        gemm_bt256<true><<<dim3(9, M / 256), 512, 0, stream>>>(
            xb, WqkvT, bqkv, qkvb, 2304, 768);
        attn_win_mfma<<<dim3(3, 49, CB), 256, 0, stream>>>(
            qkvb, ob + (size_t)c * CB * 784 * 768);
    }
    gemm_bt256<false><<<dim3(3, 98), 512, 0, stream>>>(
        ob, WprojT, bproj, out, 768, 768);
}